// Round 18
// baseline (40.380 us; speedup 1.0000x reference)
//
#include <hip/hip_runtime.h>
#include <math.h>

#define BB 2
#define NAT 2048
#define NTOK 256
#define POISON 1.0e8f
#define NPREP 1024           // k_prep blocks
#define NLDDT 128            // lddt role blocks: 8 rowblocks x 16 col-slices (128 cols each)
#define NBOND 1024           // bond role blocks: 256 rowgroups x 4 col-quarters (512 cols each)
#define NWORK 1154           // 1152 interleaved (1 lddt + 8 bond per group of 9) + 2 special

#if __has_builtin(__builtin_amdgcn_sqrtf)
#define FSQRT __builtin_amdgcn_sqrtf
#else
#define FSQRT sqrtf
#endif
#if __has_builtin(__builtin_amdgcn_exp2f)
#define FEXP2 __builtin_amdgcn_exp2f
#else
#define FEXP2 exp2f
#endif
#define FRCP __builtin_amdgcn_rcpf

struct WS {
  double mom[NPREP][17];     // per-prep-block moment partials (plain, kernel-boundary coherence)
  double pl[NLDDT][2];       // lddt partials {cem, cm}
  double pb[NBOND][2];       // bond partials {bnum, bden}
  double mse_b[BB];
  double red0[BB];           // per-batch masked-atom count n
  float wA[BB*NAT];
  float nucA[BB*NAT];
  float ligA[BB*NAT];
  // px = {x,y,z, bitcast(tok | polbit<<8)}, pg = {gx,gy,gz, mask}; masked atoms poisoned
  float4 px[BB*NAT];
  float4 pg[BB*NAT];
};

// ---------------- K1: pack (one wave per atom) + per-block moment partials ----------------
__global__ __launch_bounds__(256) void k_prep(
    const float* __restrict__ x, const float* __restrict__ xgt,
    const float* __restrict__ mask, const float* __restrict__ A,
    const float* __restrict__ poly, const float* __restrict__ lig,
    const float* __restrict__ dna, const float* __restrict__ rna,
    WS* __restrict__ ws) {
  int tid = threadIdx.x, lane = tid & 63, wv = tid >> 6, blk = blockIdx.x;
  int gid = blk * 4 + wv;                  // atom index
  int b = gid >> 11;
  float4 v = ((const float4*)(A + (size_t)gid * NTOK))[lane];
  float s = v.x * (float)(4*lane) + v.y * (float)(4*lane+1)
          + v.z * (float)(4*lane+2) + v.w * (float)(4*lane+3);
  for (int off = 32; off; off >>= 1) s += __shfl_xor(s, off);
  __shared__ double smom[4][17];
  if (lane == 0) {
    int t = (int)(s + 0.5f);
    float d  = dna[b*NTOK + t], r = rna[b*NTOK + t];
    float li = lig[b*NTOK + t], po = poly[b*NTOK + t];
    float m  = mask[gid];
    bool ok = (m != 0.0f);
    float w = 1.0f + 5.0f*d + 5.0f*r + 10.0f*li;
    ws->wA[gid]   = w;
    ws->nucA[gid] = d + r;
    ws->ligA[gid] = li;
    int meta = t | ((po != 0.0f && ok) ? 256 : 0);
    const float* xp = x   + (size_t)gid * 3;
    const float* gp = xgt + (size_t)gid * 3;
    float x0 = xp[0], x1 = xp[1], x2 = xp[2];
    float g0 = gp[0], g1 = gp[1], g2 = gp[2];
    ws->px[gid] = ok ? make_float4(x0, x1, x2, __int_as_float(meta))
                     : make_float4(POISON, POISON, POISON, __int_as_float(meta));
    ws->pg[gid] = ok ? make_float4(g0, g1, g2, m)
                     : make_float4(POISON, POISON, POISON, m);
    double wm = (double)(w * m);          // 0 for masked atoms
    double X0 = x0, X1 = x1, X2 = x2, G0 = g0, G1 = g1, G2 = g2;
    smom[wv][0] = (double)m;
    smom[wv][1] = wm;
    smom[wv][2] = wm*X0;  smom[wv][3] = wm*X1;  smom[wv][4] = wm*X2;
    smom[wv][5] = wm*G0;  smom[wv][6] = wm*G1;  smom[wv][7] = wm*G2;
    smom[wv][8]  = wm*X0*G0; smom[wv][9]  = wm*X0*G1; smom[wv][10] = wm*X0*G2;
    smom[wv][11] = wm*X1*G0; smom[wv][12] = wm*X1*G1; smom[wv][13] = wm*X1*G2;
    smom[wv][14] = wm*X2*G0; smom[wv][15] = wm*X2*G1; smom[wv][16] = wm*X2*G2;
  }
  __syncthreads();
  if (tid < 17)
    ws->mom[blk][tid] = smom[0][tid] + smom[1][tid] + smom[2][tid] + smom[3][tid];
}

// ------- 3x3 SVD: f64 moments -> f64 H -> f32 fast-math Jacobi -> R(f32), means -------
__device__ void svd3f(const double* red, float* Rf, float* muf, float* mugf) {
  double swm = red[1];
  double mugd[3] = { red[2]/swm, red[3]/swm, red[4]/swm };  // mean x
  double mud[3]  = { red[5]/swm, red[6]/swm, red[7]/swm };  // mean x_gt
  float H[3][3];
  for (int i = 0; i < 3; i++)
    for (int j = 0; j < 3; j++)
      H[i][j] = (float)(red[8 + 3*i + j] - swm * mugd[i] * mud[j]);
  float Km[3][3];
  for (int i = 0; i < 3; i++)
    for (int j = 0; j < 3; j++)
      Km[i][j] = H[0][i]*H[0][j] + H[1][i]*H[1][j] + H[2][i]*H[2][j];
  float V[3][3] = {{1,0,0},{0,1,0},{0,0,1}};
  for (int sweep = 0; sweep < 8; sweep++) {
    float off2 = Km[0][1]*Km[0][1] + Km[0][2]*Km[0][2] + Km[1][2]*Km[1][2];
    float dia2 = Km[0][0]*Km[0][0] + Km[1][1]*Km[1][1] + Km[2][2]*Km[2][2];
    if (off2 < 1e-13f * dia2 + 1e-30f) break;
    for (int p = 0; p < 2; p++) {
      for (int q = p + 1; q < 3; q++) {
        float apq = Km[p][q];
        if (fabsf(apq) < 1e-30f) continue;
        float theta = (Km[q][q] - Km[p][p]) * 0.5f * FRCP(apq);
        float t = FRCP(fabsf(theta) + FSQRT(theta*theta + 1.0f));
        if (theta < 0.0f) t = -t;
        float c = FRCP(FSQRT(t*t + 1.0f)), sn = t * c;
        for (int k = 0; k < 3; k++) {
          float akp = Km[k][p], akq = Km[k][q];
          Km[k][p] = c*akp - sn*akq;
          Km[k][q] = sn*akp + c*akq;
        }
        for (int k = 0; k < 3; k++) {
          float apk = Km[p][k], aqk = Km[q][k];
          Km[p][k] = c*apk - sn*aqk;
          Km[q][k] = sn*apk + c*aqk;
        }
        for (int k = 0; k < 3; k++) {
          float vkp = V[k][p], vkq = V[k][q];
          V[k][p] = c*vkp - sn*vkq;
          V[k][q] = sn*vkp + c*vkq;
        }
      }
    }
  }
  float ev[3] = { Km[0][0], Km[1][1], Km[2][2] };
  int id[3] = {0, 1, 2};
  for (int i = 0; i < 2; i++)
    for (int j = i + 1; j < 3; j++)
      if (ev[id[j]] > ev[id[i]]) { int tmp = id[i]; id[i] = id[j]; id[j] = tmp; }
  float Uc[3][3], Vc[3][3], S[3];
  for (int k = 0; k < 3; k++) {
    int e = id[k];
    float v0 = V[0][e], v1 = V[1][e], v2 = V[2][e];
    Vc[k][0] = v0; Vc[k][1] = v1; Vc[k][2] = v2;
    float u0 = H[0][0]*v0 + H[0][1]*v1 + H[0][2]*v2;
    float u1 = H[1][0]*v0 + H[1][1]*v1 + H[1][2]*v2;
    float u2 = H[2][0]*v0 + H[2][1]*v1 + H[2][2]*v2;
    float nrm = FSQRT(u0*u0 + u1*u1 + u2*u2);
    S[k] = nrm;
    if (nrm > 1e-12f) { float rn = FRCP(nrm); u0 *= rn; u1 *= rn; u2 *= rn; }
    Uc[k][0] = u0; Uc[k][1] = u1; Uc[k][2] = u2;
  }
  if (S[2] <= 1e-7f * (S[0] > 0.0f ? S[0] : 1.0f)) {  // degenerate fallback
    Uc[2][0] = Uc[0][1]*Uc[1][2] - Uc[0][2]*Uc[1][1];
    Uc[2][1] = Uc[0][2]*Uc[1][0] - Uc[0][0]*Uc[1][2];
    Uc[2][2] = Uc[0][0]*Uc[1][1] - Uc[0][1]*Uc[1][0];
  }
  float detU = Uc[0][0]*(Uc[1][1]*Uc[2][2]-Uc[1][2]*Uc[2][1])
             - Uc[1][0]*(Uc[0][1]*Uc[2][2]-Uc[0][2]*Uc[2][1])
             + Uc[2][0]*(Uc[0][1]*Uc[1][2]-Uc[0][2]*Uc[1][1]);
  float detV = Vc[0][0]*(Vc[1][1]*Vc[2][2]-Vc[1][2]*Vc[2][1])
             - Vc[1][0]*(Vc[0][1]*Vc[2][2]-Vc[0][2]*Vc[2][1])
             + Vc[2][0]*(Vc[0][1]*Vc[1][2]-Vc[0][2]*Vc[1][1]);
  float dsign = (detU * detV < 0.0f) ? -1.0f : 1.0f;
  for (int i = 0; i < 3; i++)
    for (int j = 0; j < 3; j++)
      Rf[3*i+j] = Uc[0][i]*Vc[0][j] + Uc[1][i]*Vc[1][j] + dsign*Uc[2][i]*Vc[2][j];
  for (int i = 0; i < 3; i++) {
    muf[i]  = (float)mud[i];
    mugf[i] = (float)mugd[i];
  }
}

// ---- K2: interleaved roles (lddt / bond / special); plain partial stores, no fences ----
__global__ __launch_bounds__(512) void k_work(const float* __restrict__ tb,
                                              WS* __restrict__ ws) {
  int tid = threadIdx.x, lane = tid & 63, wv = tid >> 6;
  const float K1 = 0.60653066f, K2 = 0.36787944f, K3 = 0.13533528f, K4 = 0.018315639f;
  const float LOG2E = 1.4426950408889634f;

  __shared__ float4 scol[256];           // [0..127]=px cols, [128..255]=pg cols
  __shared__ float2 lut[256];
  __shared__ double spart[8][17];
  __shared__ float sR[9], smu[3], smug[3];

  int role, idx;
  if (blockIdx.x < 1152) {
    int grp = blockIdx.x / 9, rem = blockIdx.x % 9;
    if (rem == 0) { role = 0; idx = grp; }            // lddt: 0..127
    else          { role = 1; idx = grp * 8 + rem - 1; }  // bond: 0..1023
  } else { role = 2; idx = blockIdx.x - 1152; }       // special: batch idx

  if (role == 0) {
    // -------- lddt: 512 rows (one per lane) x 128 columns, LUT sigmoid-sum --------
    if (tid < 256) {   // build LUT: lut[j] = {E(j/16), E((j+1)/16)-E(j/16)}
      float dd0 = (float)tid * 0.0625f;
      float Ea = FEXP2(dd0 * LOG2E);
      float Eb = FEXP2((dd0 + 0.0625f) * LOG2E);
      float e0 = FRCP(fmaf(Ea, K1, 1.0f)) + FRCP(fmaf(Ea, K2, 1.0f))
               + FRCP(fmaf(Ea, K3, 1.0f)) + FRCP(fmaf(Ea, K4, 1.0f));
      float e1 = FRCP(fmaf(Eb, K1, 1.0f)) + FRCP(fmaf(Eb, K2, 1.0f))
               + FRCP(fmaf(Eb, K3, 1.0f)) + FRCP(fmaf(Eb, K4, 1.0f));
      lut[tid] = make_float2(e0, e1 - e0);
    }
    int rowblk = idx >> 4;               // 0..7
    int cs = idx & 15;                   // column slice 0..15 (128 cols each)
    int r = rowblk * 512 + wv * 64 + lane;
    int b = r >> 11;
    int a = r & (NAT - 1);
    const float4* __restrict__ pxb = ws->px + (size_t)b * NAT;
    const float4* __restrict__ pgb = ws->pg + (size_t)b * NAT;
    float4 pa = pxb[a];
    float4 ga = pgb[a];
    float ma = ga.w;
    float th = (ws->nucA[r] > 0.5f) ? 30.0f : 15.0f;
    int cb = cs * 128;
    if (tid < 128)      scol[tid] = pxb[cb + tid];
    else if (tid < 256) scol[tid] = pgb[cb + tid - 128];
    __syncthreads();
    float cem = 0.f, cm = 0.f;
    #pragma unroll 8
    for (int j = 0; j < 128; j++) {
      float4 pc = scol[j];
      float4 gc = scol[128 + j];
      float d0 = pa.x-pc.x, d1 = pa.y-pc.y, d2 = pa.z-pc.z;
      float dxv = FSQRT(fmaf(d0, d0, fmaf(d1, d1, d2*d2)));
      float e0 = ga.x-gc.x, e1 = ga.y-gc.y, e2 = ga.z-gc.z;
      float dgv = FSQRT(fmaf(e0, e0, fmaf(e1, e1, e2*e2)));
      float t = fminf(fabsf(dxv - dgv) * 16.0f, 255.0f);
      int i0 = (int)t;
      float2 l0 = lut[i0];
      float e = fmaf(t - (float)i0, l0.y, l0.x);
      float pml = (dgv < th) ? 1.0f : 0.0f;   // masked cols poisoned -> excluded
      cem = fmaf(e, pml, cem);
      cm += pml;
    }
    if (a >= cb && a < cb + 128) { cem -= 3.2163288f; cm -= 1.0f; }  // diagonal
    cem *= 0.25f * ma;
    cm  *= ma;
    for (int off = 32; off; off >>= 1) {
      cem += __shfl_xor(cem, off);
      cm  += __shfl_xor(cm, off);
    }
    if (lane == 0) { spart[wv][0] = (double)cem; spart[wv][1] = (double)cm; }
    __syncthreads();
    if (tid < 2) {
      double s2 = 0.0;
      for (int k = 0; k < 8; k++) s2 += spart[k][tid];
      ws->pl[idx][tid] = s2;
    }
  } else if (role == 1) {
    // -------- bond: 16 rows (2 per wave) x 512-column quarter --------
    int rowblk = idx >> 2;               // 0..255
    int quarter = idx & 3;
    int gid0 = rowblk * 16 + wv * 2, gid1 = gid0 + 1;
    int b = gid0 >> 11;
    int a0 = gid0 & (NAT - 1), a1 = a0 + 1;
    const float4* __restrict__ pxb = ws->px + (size_t)b * NAT;
    const float4* __restrict__ pgb = ws->pg + (size_t)b * NAT;
    float4 pa0 = pxb[a0], pa1 = pxb[a1];
    float4 ga0 = pgb[a0], ga1 = pgb[a1];
    float lm0 = ws->ligA[gid0] * ga0.w, lm1 = ws->ligA[gid1] * ga1.w;
    float bnum0 = 0.f, bden0 = 0.f, bnum1 = 0.f, bden1 = 0.f;
    if (lm0 != 0.0f || lm1 != 0.0f) {
      const float* __restrict__ tbrow0 = tb + ((size_t)b * NTOK + (__float_as_int(pa0.w) & 255)) * NTOK;
      const float* __restrict__ tbrow1 = tb + ((size_t)b * NTOK + (__float_as_int(pa1.w) & 255)) * NTOK;
      int base = quarter * 512;
      #pragma unroll 8
      for (int k = 0; k < 8; k++) {
        int c = base + 64 * k + lane;
        float4 pc = pxb[c];
        float4 gc = pgb[c];
        int meta = __float_as_int(pc.w);
        float pol = (meta & 256) ? 1.0f : 0.0f;
        float tv0 = tbrow0[meta & 255] * pol;
        float tv1 = tbrow1[meta & 255] * pol;
        float d0 = pa0.x-pc.x, d1 = pa0.y-pc.y, d2 = pa0.z-pc.z;
        float dxv0 = FSQRT(fmaf(d0, d0, fmaf(d1, d1, d2*d2)));
        float e0 = ga0.x-gc.x, e1 = ga0.y-gc.y, e2 = ga0.z-gc.z;
        float dgv0 = FSQRT(fmaf(e0, e0, fmaf(e1, e1, e2*e2)));
        float diff0 = dxv0 - dgv0;
        float f0 = pa1.x-pc.x, f1 = pa1.y-pc.y, f2 = pa1.z-pc.z;
        float dxv1 = FSQRT(fmaf(f0, f0, fmaf(f1, f1, f2*f2)));
        float h0 = ga1.x-gc.x, h1 = ga1.y-gc.y, h2 = ga1.z-gc.z;
        float dgv1 = FSQRT(fmaf(h0, h0, fmaf(h1, h1, h2*h2)));
        float diff1 = dxv1 - dgv1;
        bnum0 += diff0 * diff0 * tv0;  bden0 += tv0;
        bnum1 += diff1 * diff1 * tv1;  bden1 += tv1;
      }
    }
    float vn = lm0 * bnum0 + lm1 * bnum1;
    float vd = lm0 * bden0 + lm1 * bden1;
    for (int off = 32; off; off >>= 1) {
      vn += __shfl_xor(vn, off);
      vd += __shfl_xor(vd, off);
    }
    if (lane == 0) { spart[wv][0] = (double)vn; spart[wv][1] = (double)vd; }
    __syncthreads();
    if (tid < 2) {
      double s2 = 0.0;
      for (int k = 0; k < 8; k++) s2 += spart[k][tid];
      ws->pb[idx][tid] = s2;
    }
  } else {
    // -------- special: per-batch moments reduce + f32 SVD + MSE (concurrent with bulk) --------
    int b = idx;
    double acc[17];
    {
      int s2 = b * 512 + tid;              // one mom slot per thread
      for (int k = 0; k < 17; k++) acc[k] = ws->mom[s2][k];
    }
    for (int k = 0; k < 17; k++)
      for (int off = 32; off; off >>= 1) acc[k] += __shfl_xor(acc[k], off);
    if (lane == 0)
      for (int k = 0; k < 17; k++) spart[wv][k] = acc[k];
    __syncthreads();
    __shared__ double sred[17];
    if (tid < 17) {
      double s2 = 0.0;
      for (int k = 0; k < 8; k++) s2 += spart[k][tid];
      sred[tid] = s2;
    }
    __syncthreads();
    if (tid == 0) svd3f(sred, sR, smu, smug);
    __syncthreads();
    double msea = 0.0;
    for (int a2 = tid; a2 < NAT; a2 += 512) {
      int gid = b * NAT + a2;
      float4 pa = ws->px[gid];
      float4 ga = ws->pg[gid];
      float ma = ga.w;
      if (ma != 0.0f) {
        float c0 = ga.x - smu[0], c1 = ga.y - smu[1], c2 = ga.z - smu[2];
        float q0 = pa.x - (sR[0]*c0 + sR[1]*c1 + sR[2]*c2 + smug[0]);
        float q1 = pa.y - (sR[3]*c0 + sR[4]*c1 + sR[5]*c2 + smug[1]);
        float q2 = pa.z - (sR[6]*c0 + sR[7]*c1 + sR[8]*c2 + smug[2]);
        msea += (double)(ws->wA[gid] * ma * (q0*q0 + q1*q1 + q2*q2));
      }
    }
    for (int off = 32; off; off >>= 1) msea += __shfl_xor(msea, off);
    if (lane == 0) spart[wv][0] = msea;
    __syncthreads();
    if (tid == 0) {
      ws->mse_b[b] = spart[0][0] + spart[1][0] + spart[2][0] + spart[3][0]
                   + spart[4][0] + spart[5][0] + spart[6][0] + spart[7][0];
      ws->red0[b]  = sred[0];
    }
  }
}

// ---------------- K3: final combine (one block; kernel boundary = coherence) ----------------
__global__ __launch_bounds__(256) void k_tail(const WS* __restrict__ ws,
                                              float* __restrict__ out) {
  int tid = threadIdx.x, lane = tid & 63, wv = tid >> 6;
  double acc8[8];                        // {cem,cm,bnum,bden} x 2 batches
  for (int k = 0; k < 8; k++) acc8[k] = 0.0;
  if (tid < NLDDT) {                     // 128 lddt slots; batch = idx>>6
    int bb = tid >> 6;
    acc8[bb*4+0] = ws->pl[tid][0];
    acc8[bb*4+1] = ws->pl[tid][1];
  }
  for (int s = tid; s < NBOND; s += 256) {  // 1024 bond slots; batch = idx>>9
    int bb = s >> 9;
    acc8[bb*4+2] += ws->pb[s][0];
    acc8[bb*4+3] += ws->pb[s][1];
  }
  for (int k = 0; k < 8; k++)
    for (int off = 32; off; off >>= 1) acc8[k] += __shfl_xor(acc8[k], off);
  __shared__ double spart[4][8];
  if (lane == 0)
    for (int k = 0; k < 8; k++) spart[wv][k] = acc8[k];
  __syncthreads();
  if (tid == 0) {
    double t8[8];
    for (int k = 0; k < 8; k++)
      t8[k] = spart[0][k] + spart[1][k] + spart[2][k] + spart[3][k];
    double mse_num = ws->mse_b[0] + ws->mse_b[1];
    const double wt = (4.0*4.0 + 16.0*16.0) / ((4.0+16.0)*(4.0+16.0));  // 0.68
    double lsum = 0.0;
    for (int bb = 0; bb < BB; bb++) {
      double lmse  = mse_num / (3.0 * ws->red0[bb]);
      double lddt  = t8[bb*4+0] / t8[bb*4+1];
      double lbond = t8[bb*4+2] / t8[bb*4+3];
      lsum += wt * (lmse + lbond) + (1.0 - lddt);
    }
    out[0] = (float)(lsum / BB);
  }
}

extern "C" void kernel_launch(void* const* d_in, const int* in_sizes, int n_in,
                              void* d_out, int out_size, void* d_ws, size_t ws_size,
                              hipStream_t stream) {
  const float* x    = (const float*)d_in[0];
  const float* xgt  = (const float*)d_in[1];
  const float* mask = (const float*)d_in[2];
  const float* A    = (const float*)d_in[3];
  const float* tb   = (const float*)d_in[4];
  const float* poly = (const float*)d_in[5];
  const float* lig  = (const float*)d_in[6];
  const float* dna  = (const float*)d_in[7];
  const float* rna  = (const float*)d_in[8];
  WS* ws = (WS*)d_ws;
  float* out = (float*)d_out;

  k_prep<<<NPREP, 256, 0, stream>>>(x, xgt, mask, A, poly, lig, dna, rna, ws);
  k_work<<<NWORK, 512, 0, stream>>>(tb, ws);
  k_tail<<<1, 256, 0, stream>>>(ws, out);
}

// Round 19
// 35.408 us; speedup vs baseline: 1.1404x; 1.1404x over previous
//
#include <hip/hip_runtime.h>
#include <math.h>

#define BB 2
#define NAT 2048
#define NTOK 256
#define POISON 1.0e8f
#define NPREP 1024           // k_prep blocks
#define NLDDT 128            // lddt role blocks: 8 rowblocks x 16 col-slices (128 cols each)
#define NBOND 256            // bond role blocks
#define NWORK 386            // 384 interleaved (1 lddt + 2 bond per group of 3) + 2 special

#if __has_builtin(__builtin_amdgcn_sqrtf)
#define FSQRT __builtin_amdgcn_sqrtf
#else
#define FSQRT sqrtf
#endif
#if __has_builtin(__builtin_amdgcn_exp2f)
#define FEXP2 __builtin_amdgcn_exp2f
#else
#define FEXP2 exp2f
#endif
#define FRCP __builtin_amdgcn_rcpf

struct WS {
  double mom[NPREP][17];     // per-prep-block moment partials (plain, kernel-boundary coherence)
  double pl[NLDDT][2];       // lddt partials {cem, cm}
  double pb[NBOND][2];       // bond partials {bnum, bden}
  double mse_b[BB];
  double red0[BB];           // per-batch masked-atom count n
  float wA[BB*NAT];
  float nucA[BB*NAT];
  float ligA[BB*NAT];
  // px = {x,y,z, bitcast(tok | polbit<<8)}, pg = {gx,gy,gz, mask}; masked atoms poisoned
  float4 px[BB*NAT];
  float4 pg[BB*NAT];
};

// ---------------- K1: pack (one wave per atom) + per-block moment partials ----------------
__global__ __launch_bounds__(256) void k_prep(
    const float* __restrict__ x, const float* __restrict__ xgt,
    const float* __restrict__ mask, const float* __restrict__ A,
    const float* __restrict__ poly, const float* __restrict__ lig,
    const float* __restrict__ dna, const float* __restrict__ rna,
    WS* __restrict__ ws) {
  int tid = threadIdx.x, lane = tid & 63, wv = tid >> 6, blk = blockIdx.x;
  int gid = blk * 4 + wv;                  // atom index
  int b = gid >> 11;
  float4 v = ((const float4*)(A + (size_t)gid * NTOK))[lane];
  float s = v.x * (float)(4*lane) + v.y * (float)(4*lane+1)
          + v.z * (float)(4*lane+2) + v.w * (float)(4*lane+3);
  for (int off = 32; off; off >>= 1) s += __shfl_xor(s, off);
  __shared__ double smom[4][17];
  if (lane == 0) {
    int t = (int)(s + 0.5f);
    float d  = dna[b*NTOK + t], r = rna[b*NTOK + t];
    float li = lig[b*NTOK + t], po = poly[b*NTOK + t];
    float m  = mask[gid];
    bool ok = (m != 0.0f);
    float w = 1.0f + 5.0f*d + 5.0f*r + 10.0f*li;
    ws->wA[gid]   = w;
    ws->nucA[gid] = d + r;
    ws->ligA[gid] = li;
    int meta = t | ((po != 0.0f && ok) ? 256 : 0);
    const float* xp = x   + (size_t)gid * 3;
    const float* gp = xgt + (size_t)gid * 3;
    float x0 = xp[0], x1 = xp[1], x2 = xp[2];
    float g0 = gp[0], g1 = gp[1], g2 = gp[2];
    ws->px[gid] = ok ? make_float4(x0, x1, x2, __int_as_float(meta))
                     : make_float4(POISON, POISON, POISON, __int_as_float(meta));
    ws->pg[gid] = ok ? make_float4(g0, g1, g2, m)
                     : make_float4(POISON, POISON, POISON, m);
    double wm = (double)(w * m);          // 0 for masked atoms
    double X0 = x0, X1 = x1, X2 = x2, G0 = g0, G1 = g1, G2 = g2;
    smom[wv][0] = (double)m;
    smom[wv][1] = wm;
    smom[wv][2] = wm*X0;  smom[wv][3] = wm*X1;  smom[wv][4] = wm*X2;
    smom[wv][5] = wm*G0;  smom[wv][6] = wm*G1;  smom[wv][7] = wm*G2;
    smom[wv][8]  = wm*X0*G0; smom[wv][9]  = wm*X0*G1; smom[wv][10] = wm*X0*G2;
    smom[wv][11] = wm*X1*G0; smom[wv][12] = wm*X1*G1; smom[wv][13] = wm*X1*G2;
    smom[wv][14] = wm*X2*G0; smom[wv][15] = wm*X2*G1; smom[wv][16] = wm*X2*G2;
  }
  __syncthreads();
  if (tid < 17)
    ws->mom[blk][tid] = smom[0][tid] + smom[1][tid] + smom[2][tid] + smom[3][tid];
}

// ------- 3x3 SVD: f64 moments -> f64 H -> f32 fast-math Jacobi -> R(f32), means -------
__device__ void svd3f(const double* red, float* Rf, float* muf, float* mugf) {
  double swm = red[1];
  double mugd[3] = { red[2]/swm, red[3]/swm, red[4]/swm };  // mean x
  double mud[3]  = { red[5]/swm, red[6]/swm, red[7]/swm };  // mean x_gt
  float H[3][3];
  for (int i = 0; i < 3; i++)
    for (int j = 0; j < 3; j++)
      H[i][j] = (float)(red[8 + 3*i + j] - swm * mugd[i] * mud[j]);
  float Km[3][3];
  for (int i = 0; i < 3; i++)
    for (int j = 0; j < 3; j++)
      Km[i][j] = H[0][i]*H[0][j] + H[1][i]*H[1][j] + H[2][i]*H[2][j];
  float V[3][3] = {{1,0,0},{0,1,0},{0,0,1}};
  for (int sweep = 0; sweep < 8; sweep++) {
    float off2 = Km[0][1]*Km[0][1] + Km[0][2]*Km[0][2] + Km[1][2]*Km[1][2];
    float dia2 = Km[0][0]*Km[0][0] + Km[1][1]*Km[1][1] + Km[2][2]*Km[2][2];
    if (off2 < 1e-13f * dia2 + 1e-30f) break;
    for (int p = 0; p < 2; p++) {
      for (int q = p + 1; q < 3; q++) {
        float apq = Km[p][q];
        if (fabsf(apq) < 1e-30f) continue;
        float theta = (Km[q][q] - Km[p][p]) * 0.5f * FRCP(apq);
        float t = FRCP(fabsf(theta) + FSQRT(theta*theta + 1.0f));
        if (theta < 0.0f) t = -t;
        float c = FRCP(FSQRT(t*t + 1.0f)), sn = t * c;
        for (int k = 0; k < 3; k++) {
          float akp = Km[k][p], akq = Km[k][q];
          Km[k][p] = c*akp - sn*akq;
          Km[k][q] = sn*akp + c*akq;
        }
        for (int k = 0; k < 3; k++) {
          float apk = Km[p][k], aqk = Km[q][k];
          Km[p][k] = c*apk - sn*aqk;
          Km[q][k] = sn*apk + c*aqk;
        }
        for (int k = 0; k < 3; k++) {
          float vkp = V[k][p], vkq = V[k][q];
          V[k][p] = c*vkp - sn*vkq;
          V[k][q] = sn*vkp + c*vkq;
        }
      }
    }
  }
  float ev[3] = { Km[0][0], Km[1][1], Km[2][2] };
  int id[3] = {0, 1, 2};
  for (int i = 0; i < 2; i++)
    for (int j = i + 1; j < 3; j++)
      if (ev[id[j]] > ev[id[i]]) { int tmp = id[i]; id[i] = id[j]; id[j] = tmp; }
  float Uc[3][3], Vc[3][3], S[3];
  for (int k = 0; k < 3; k++) {
    int e = id[k];
    float v0 = V[0][e], v1 = V[1][e], v2 = V[2][e];
    Vc[k][0] = v0; Vc[k][1] = v1; Vc[k][2] = v2;
    float u0 = H[0][0]*v0 + H[0][1]*v1 + H[0][2]*v2;
    float u1 = H[1][0]*v0 + H[1][1]*v1 + H[1][2]*v2;
    float u2 = H[2][0]*v0 + H[2][1]*v1 + H[2][2]*v2;
    float nrm = FSQRT(u0*u0 + u1*u1 + u2*u2);
    S[k] = nrm;
    if (nrm > 1e-12f) { float rn = FRCP(nrm); u0 *= rn; u1 *= rn; u2 *= rn; }
    Uc[k][0] = u0; Uc[k][1] = u1; Uc[k][2] = u2;
  }
  if (S[2] <= 1e-7f * (S[0] > 0.0f ? S[0] : 1.0f)) {  // degenerate fallback
    Uc[2][0] = Uc[0][1]*Uc[1][2] - Uc[0][2]*Uc[1][1];
    Uc[2][1] = Uc[0][2]*Uc[1][0] - Uc[0][0]*Uc[1][2];
    Uc[2][2] = Uc[0][0]*Uc[1][1] - Uc[0][1]*Uc[1][0];
  }
  float detU = Uc[0][0]*(Uc[1][1]*Uc[2][2]-Uc[1][2]*Uc[2][1])
             - Uc[1][0]*(Uc[0][1]*Uc[2][2]-Uc[0][2]*Uc[2][1])
             + Uc[2][0]*(Uc[0][1]*Uc[1][2]-Uc[0][2]*Uc[1][1]);
  float detV = Vc[0][0]*(Vc[1][1]*Vc[2][2]-Vc[1][2]*Vc[2][1])
             - Vc[1][0]*(Vc[0][1]*Vc[2][2]-Vc[0][2]*Vc[2][1])
             + Vc[2][0]*(Vc[0][1]*Vc[1][2]-Vc[0][2]*Vc[1][1]);
  float dsign = (detU * detV < 0.0f) ? -1.0f : 1.0f;
  for (int i = 0; i < 3; i++)
    for (int j = 0; j < 3; j++)
      Rf[3*i+j] = Uc[0][i]*Vc[0][j] + Uc[1][i]*Vc[1][j] + dsign*Uc[2][i]*Vc[2][j];
  for (int i = 0; i < 3; i++) {
    muf[i]  = (float)mud[i];
    mugf[i] = (float)mugd[i];
  }
}

// ---- K2: interleaved roles (lddt / bond / special); plain partial stores, no fences ----
__global__ __launch_bounds__(512) void k_work(const float* __restrict__ tb,
                                              WS* __restrict__ ws) {
  int tid = threadIdx.x, lane = tid & 63, wv = tid >> 6;
  const float K1 = 0.60653066f, K2 = 0.36787944f, K3 = 0.13533528f, K4 = 0.018315639f;
  const float LOG2E = 1.4426950408889634f;

  __shared__ float4 scol[256];           // [0..127]=px cols, [128..255]=pg cols
  __shared__ float2 lut[256];
  __shared__ double spart[8][17];
  __shared__ float sR[9], smu[3], smug[3];

  int role, idx;
  if (blockIdx.x < 384) {
    int grp = blockIdx.x / 3, rem = blockIdx.x % 3;
    if (rem == 0) { role = 0; idx = grp; }            // lddt: 0..127
    else          { role = 1; idx = grp * 2 + rem - 1; }  // bond: 0..255
  } else { role = 2; idx = blockIdx.x - 384; }        // special: batch idx

  if (role == 0) {
    // -------- lddt: 512 rows (one per lane) x 128 columns, LUT sigmoid-sum --------
    if (tid < 256) {   // build LUT: lut[j] = {E(j/16), E((j+1)/16)-E(j/16)}
      float dd0 = (float)tid * 0.0625f;
      float Ea = FEXP2(dd0 * LOG2E);
      float Eb = FEXP2((dd0 + 0.0625f) * LOG2E);
      float e0 = FRCP(fmaf(Ea, K1, 1.0f)) + FRCP(fmaf(Ea, K2, 1.0f))
               + FRCP(fmaf(Ea, K3, 1.0f)) + FRCP(fmaf(Ea, K4, 1.0f));
      float e1 = FRCP(fmaf(Eb, K1, 1.0f)) + FRCP(fmaf(Eb, K2, 1.0f))
               + FRCP(fmaf(Eb, K3, 1.0f)) + FRCP(fmaf(Eb, K4, 1.0f));
      lut[tid] = make_float2(e0, e1 - e0);
    }
    int rowblk = idx >> 4;               // 0..7
    int cs = idx & 15;                   // column slice 0..15 (128 cols each)
    int r = rowblk * 512 + wv * 64 + lane;
    int b = r >> 11;
    int a = r & (NAT - 1);
    const float4* __restrict__ pxb = ws->px + (size_t)b * NAT;
    const float4* __restrict__ pgb = ws->pg + (size_t)b * NAT;
    float4 pa = pxb[a];
    float4 ga = pgb[a];
    float ma = ga.w;
    float th = (ws->nucA[r] > 0.5f) ? 30.0f : 15.0f;
    int cb = cs * 128;
    if (tid < 128)      scol[tid] = pxb[cb + tid];
    else if (tid < 256) scol[tid] = pgb[cb + tid - 128];
    __syncthreads();
    float cem = 0.f, cm = 0.f;
    #pragma unroll 8
    for (int j = 0; j < 128; j++) {
      float4 pc = scol[j];
      float4 gc = scol[128 + j];
      float d0 = pa.x-pc.x, d1 = pa.y-pc.y, d2 = pa.z-pc.z;
      float dxv = FSQRT(fmaf(d0, d0, fmaf(d1, d1, d2*d2)));
      float e0 = ga.x-gc.x, e1 = ga.y-gc.y, e2 = ga.z-gc.z;
      float dgv = FSQRT(fmaf(e0, e0, fmaf(e1, e1, e2*e2)));
      float t = fminf(fabsf(dxv - dgv) * 16.0f, 255.0f);
      int i0 = (int)t;
      float2 l0 = lut[i0];
      float e = fmaf(t - (float)i0, l0.y, l0.x);
      float pml = (dgv < th) ? 1.0f : 0.0f;   // masked cols poisoned -> excluded
      cem = fmaf(e, pml, cem);
      cm += pml;
    }
    if (a >= cb && a < cb + 128) { cem -= 3.2163288f; cm -= 1.0f; }  // diagonal
    cem *= 0.25f * ma;
    cm  *= ma;
    for (int off = 32; off; off >>= 1) {
      cem += __shfl_xor(cem, off);
      cm  += __shfl_xor(cm, off);
    }
    if (lane == 0) { spart[wv][0] = (double)cem; spart[wv][1] = (double)cm; }
    __syncthreads();
    if (tid < 2) {
      double s2 = 0.0;
      for (int k = 0; k < 8; k++) s2 += spart[k][tid];
      ws->pl[idx][tid] = s2;
    }
  } else if (role == 1) {
    // -------- bond: 16 rows per block (2 per wave), all 2048 columns --------
    int gid0 = idx * 16 + wv * 2, gid1 = gid0 + 1;
    int b = gid0 >> 11;
    int a0 = gid0 & (NAT - 1), a1 = a0 + 1;
    const float4* __restrict__ pxb = ws->px + (size_t)b * NAT;
    const float4* __restrict__ pgb = ws->pg + (size_t)b * NAT;
    float4 pa0 = pxb[a0], pa1 = pxb[a1];
    float4 ga0 = pgb[a0], ga1 = pgb[a1];
    float lm0 = ws->ligA[gid0] * ga0.w, lm1 = ws->ligA[gid1] * ga1.w;
    float bnum0 = 0.f, bden0 = 0.f, bnum1 = 0.f, bden1 = 0.f;
    if (lm0 != 0.0f || lm1 != 0.0f) {
      const float* __restrict__ tbrow0 = tb + ((size_t)b * NTOK + (__float_as_int(pa0.w) & 255)) * NTOK;
      const float* __restrict__ tbrow1 = tb + ((size_t)b * NTOK + (__float_as_int(pa1.w) & 255)) * NTOK;
      #pragma unroll 8
      for (int k = 0; k < NAT / 64; k++) {
        int c = 64 * k + lane;
        float4 pc = pxb[c];
        float4 gc = pgb[c];
        int meta = __float_as_int(pc.w);
        float pol = (meta & 256) ? 1.0f : 0.0f;
        float tv0 = tbrow0[meta & 255] * pol;
        float tv1 = tbrow1[meta & 255] * pol;
        float d0 = pa0.x-pc.x, d1 = pa0.y-pc.y, d2 = pa0.z-pc.z;
        float dxv0 = FSQRT(fmaf(d0, d0, fmaf(d1, d1, d2*d2)));
        float e0 = ga0.x-gc.x, e1 = ga0.y-gc.y, e2 = ga0.z-gc.z;
        float dgv0 = FSQRT(fmaf(e0, e0, fmaf(e1, e1, e2*e2)));
        float diff0 = dxv0 - dgv0;
        float f0 = pa1.x-pc.x, f1 = pa1.y-pc.y, f2 = pa1.z-pc.z;
        float dxv1 = FSQRT(fmaf(f0, f0, fmaf(f1, f1, f2*f2)));
        float h0 = ga1.x-gc.x, h1 = ga1.y-gc.y, h2 = ga1.z-gc.z;
        float dgv1 = FSQRT(fmaf(h0, h0, fmaf(h1, h1, h2*h2)));
        float diff1 = dxv1 - dgv1;
        bnum0 += diff0 * diff0 * tv0;  bden0 += tv0;
        bnum1 += diff1 * diff1 * tv1;  bden1 += tv1;
      }
    }
    float vn = lm0 * bnum0 + lm1 * bnum1;
    float vd = lm0 * bden0 + lm1 * bden1;
    for (int off = 32; off; off >>= 1) {
      vn += __shfl_xor(vn, off);
      vd += __shfl_xor(vd, off);
    }
    if (lane == 0) { spart[wv][0] = (double)vn; spart[wv][1] = (double)vd; }
    __syncthreads();
    if (tid < 2) {
      double s2 = 0.0;
      for (int k = 0; k < 8; k++) s2 += spart[k][tid];
      ws->pb[idx][tid] = s2;
    }
  } else {
    // -------- special: per-batch moments reduce + f32 SVD + MSE (concurrent with bulk) --------
    int b = idx;
    double acc[17];
    {
      int s2 = b * 512 + tid;              // one mom slot per thread
      for (int k = 0; k < 17; k++) acc[k] = ws->mom[s2][k];
    }
    for (int k = 0; k < 17; k++)
      for (int off = 32; off; off >>= 1) acc[k] += __shfl_xor(acc[k], off);
    if (lane == 0)
      for (int k = 0; k < 17; k++) spart[wv][k] = acc[k];
    __syncthreads();
    __shared__ double sred[17];
    if (tid < 17) {
      double s2 = 0.0;
      for (int k = 0; k < 8; k++) s2 += spart[k][tid];
      sred[tid] = s2;
    }
    __syncthreads();
    if (tid == 0) svd3f(sred, sR, smu, smug);
    __syncthreads();
    double msea = 0.0;
    for (int a2 = tid; a2 < NAT; a2 += 512) {
      int gid = b * NAT + a2;
      float4 pa = ws->px[gid];
      float4 ga = ws->pg[gid];
      float ma = ga.w;
      if (ma != 0.0f) {
        float c0 = ga.x - smu[0], c1 = ga.y - smu[1], c2 = ga.z - smu[2];
        float q0 = pa.x - (sR[0]*c0 + sR[1]*c1 + sR[2]*c2 + smug[0]);
        float q1 = pa.y - (sR[3]*c0 + sR[4]*c1 + sR[5]*c2 + smug[1]);
        float q2 = pa.z - (sR[6]*c0 + sR[7]*c1 + sR[8]*c2 + smug[2]);
        msea += (double)(ws->wA[gid] * ma * (q0*q0 + q1*q1 + q2*q2));
      }
    }
    for (int off = 32; off; off >>= 1) msea += __shfl_xor(msea, off);
    if (lane == 0) spart[wv][0] = msea;
    __syncthreads();
    if (tid == 0) {
      ws->mse_b[b] = spart[0][0] + spart[1][0] + spart[2][0] + spart[3][0]
                   + spart[4][0] + spart[5][0] + spart[6][0] + spart[7][0];
      ws->red0[b]  = sred[0];
    }
  }
}

// ---------------- K3: final combine (one block; kernel boundary = coherence) ----------------
__global__ __launch_bounds__(256) void k_tail(const WS* __restrict__ ws,
                                              float* __restrict__ out) {
  int tid = threadIdx.x, lane = tid & 63, wv = tid >> 6;
  double acc8[8];                        // {cem,cm,bnum,bden} x 2 batches
  for (int k = 0; k < 8; k++) acc8[k] = 0.0;
  if (tid < NLDDT) {                     // 128 lddt slots; batch = idx>>6
    int bb = tid >> 6;
    acc8[bb*4+0] = ws->pl[tid][0];
    acc8[bb*4+1] = ws->pl[tid][1];
  }
  {
    int bb = tid >> 7;                   // 256 bond slots; batch = idx>>7
    acc8[bb*4+2] = ws->pb[tid][0];
    acc8[bb*4+3] = ws->pb[tid][1];
  }
  for (int k = 0; k < 8; k++)
    for (int off = 32; off; off >>= 1) acc8[k] += __shfl_xor(acc8[k], off);
  __shared__ double spart[4][8];
  if (lane == 0)
    for (int k = 0; k < 8; k++) spart[wv][k] = acc8[k];
  __syncthreads();
  if (tid == 0) {
    double t8[8];
    for (int k = 0; k < 8; k++)
      t8[k] = spart[0][k] + spart[1][k] + spart[2][k] + spart[3][k];
    double mse_num = ws->mse_b[0] + ws->mse_b[1];
    const double wt = (4.0*4.0 + 16.0*16.0) / ((4.0+16.0)*(4.0+16.0));  // 0.68
    double lsum = 0.0;
    for (int bb = 0; bb < BB; bb++) {
      double lmse  = mse_num / (3.0 * ws->red0[bb]);
      double lddt  = t8[bb*4+0] / t8[bb*4+1];
      double lbond = t8[bb*4+2] / t8[bb*4+3];
      lsum += wt * (lmse + lbond) + (1.0 - lddt);
    }
    out[0] = (float)(lsum / BB);
  }
}

extern "C" void kernel_launch(void* const* d_in, const int* in_sizes, int n_in,
                              void* d_out, int out_size, void* d_ws, size_t ws_size,
                              hipStream_t stream) {
  const float* x    = (const float*)d_in[0];
  const float* xgt  = (const float*)d_in[1];
  const float* mask = (const float*)d_in[2];
  const float* A    = (const float*)d_in[3];
  const float* tb   = (const float*)d_in[4];
  const float* poly = (const float*)d_in[5];
  const float* lig  = (const float*)d_in[6];
  const float* dna  = (const float*)d_in[7];
  const float* rna  = (const float*)d_in[8];
  WS* ws = (WS*)d_ws;
  float* out = (float*)d_out;

  k_prep<<<NPREP, 256, 0, stream>>>(x, xgt, mask, A, poly, lig, dna, rna, ws);
  k_work<<<NWORK, 512, 0, stream>>>(tb, ws);
  k_tail<<<1, 256, 0, stream>>>(ws, out);
}